// Round 6
// baseline (309.543 us; speedup 1.0000x reference)
//
#include <hip/hip_runtime.h>
#include <math.h>

#define BATCH 4
#define NPTS  8192
#define KNN   16
#define KK    17               // top-17 incl. self (self key: d2 = +0 exactly)
#define NQ    (BATCH*NPTS)     // 32768
#define JMASK 0x1FFFu
#define EMASK 0xFFFFE000u      // top 19 bits of d2 (d2 >= +0 -> uint-sortable)
#define TOTAL_EDGES (BATCH*NPTS*KNN)

#define GC    32
#define GLO   (-4.5f)
#define GINV  (32.0f/9.0f)
#define NCELL (GC*GC*GC)

#define NSG   512              // candidate subgroups per batch (16 pts each)
#define SGS   16

#define QPW   8                // queries per wave (8 lanes per query)
#define GRIDQ (NQ/QPW)         // 4096 one-wave blocks
#define WIN   64               // tau0 window (sorted-index neighbors)

__device__ __forceinline__ int cell_coord(float x) {
    int c = (int)floorf((x - GLO) * GINV);
    return min(GC - 1, max(0, c));
}
__device__ __forceinline__ unsigned spread5(unsigned v) {
    v &= 31u;
    v = (v | (v << 8)) & 0x100Fu;
    v = (v | (v << 4)) & 0x10C3u;
    v = (v | (v << 2)) & 0x1249u;
    return v;
}
__device__ __forceinline__ unsigned morton_id(float x, float y, float z) {
    return spread5((unsigned)cell_coord(x)) | (spread5((unsigned)cell_coord(y)) << 1)
         | (spread5((unsigned)cell_coord(z)) << 2);
}
// p = (-2xj,-2yj,-2zj,sqj); key = truncated d2 | index (self -> d2 = +0 exact)
__device__ __forceinline__ unsigned mkkey(const float4 p, float xi, float yi,
                                          float zi, float sqi, unsigned j) {
    const float e  = fmaf(p.x, xi, fmaf(p.y, yi, p.z * zi)) + p.w;
    const float d2 = e + sqi;
    return (__float_as_uint(d2) & EMASK) | j;
}
__device__ __forceinline__ void ins17(unsigned (&a)[KK], unsigned key) {
    #pragma unroll
    for (int k = KK - 1; k >= 1; --k) a[k] = min(a[k], max(a[k - 1], key));
    a[0] = min(a[0], key);
}

// ---- build kernels (verified, absmax 0.0) ----
__global__ void pel_hist(const float* __restrict__ pref, unsigned* __restrict__ hist,
                         float* __restrict__ acc, unsigned* __restrict__ bcnt) {
    const int idx = blockIdx.x * 256 + threadIdx.x;
    if (idx == 0) { acc[0] = 0.0f; bcnt[0] = 0u; }
    const int b = idx >> 13;
    const unsigned mid = morton_id(pref[3*idx], pref[3*idx+1], pref[3*idx+2]);
    atomicAdd(&hist[b * NCELL + mid], 1u);
}
__global__ __launch_bounds__(1024)
void pel_scan(const unsigned* __restrict__ hist, unsigned* __restrict__ off) {
    __shared__ unsigned s[1024];
    const unsigned* h = hist + blockIdx.x * NCELL;
    unsigned*       o = off  + blockIdx.x * NCELL;
    const int t = threadIdx.x;
    unsigned v[32], tot = 0;
    #pragma unroll
    for (int k = 0; k < 32; ++k) { v[k] = h[t * 32 + k]; tot += v[k]; }
    s[t] = tot;
    __syncthreads();
    for (int d = 1; d < 1024; d <<= 1) {
        const unsigned add = (t >= d) ? s[t - d] : 0u;
        __syncthreads();
        s[t] += add;
        __syncthreads();
    }
    unsigned run = s[t] - tot;
    #pragma unroll
    for (int k = 0; k < 32; ++k) { o[t * 32 + k] = run; run += v[k]; }
}
__global__ void pel_scatter(const float* __restrict__ pref, const float* __restrict__ pts,
                            unsigned* __restrict__ off,
                            float4* __restrict__ p4r, float4* __restrict__ p4p) {
    const int idx = blockIdx.x * 256 + threadIdx.x;
    const int b = idx >> 13;
    const float x = pref[3*idx], y = pref[3*idx+1], z = pref[3*idx+2];
    const unsigned mid = morton_id(x, y, z);
    const unsigned pos = atomicAdd(&off[b * NCELL + mid], 1u);
    p4r[b * NPTS + pos] = make_float4(-2.f*x, -2.f*y, -2.f*z, fmaf(x, x, fmaf(y, y, z*z)));
    const float px = pts[3*idx], py = pts[3*idx+1], pz = pts[3*idx+2];
    p4p[b * NPTS + pos] = make_float4(-2.f*px, -2.f*py, -2.f*pz,
                                      fmaf(px, px, fmaf(py, py, pz*pz)));
}
// subgroup bounding balls: one 16-lane group per 16-point subgroup
__global__ __launch_bounds__(256)
void pel_gstat(const float4* __restrict__ P4r, float4* __restrict__ sgball) {
    const int quad = threadIdx.x >> 4, pos = threadIdx.x & 15;
    const int gid = blockIdx.x * 16 + quad;          // 0 .. BATCH*NSG-1
    const int b = gid >> 9, s = gid & (NSG - 1);
    const float4 p = P4r[b * NPTS + s * SGS + pos];
    const float x = -0.5f * p.x, y = -0.5f * p.y, z = -0.5f * p.z;
    float mnx = x, mxx = x, mny = y, mxy = y, mnz = z, mxz = z;
    #pragma unroll
    for (int m = 1; m <= 8; m <<= 1) {
        mnx = fminf(mnx, __shfl_xor(mnx, m, 64)); mxx = fmaxf(mxx, __shfl_xor(mxx, m, 64));
        mny = fminf(mny, __shfl_xor(mny, m, 64)); mxy = fmaxf(mxy, __shfl_xor(mxy, m, 64));
        mnz = fminf(mnz, __shfl_xor(mnz, m, 64)); mxz = fmaxf(mxz, __shfl_xor(mxz, m, 64));
    }
    const float cx = 0.5f * (mnx + mxx), cy = 0.5f * (mny + mxy), cz = 0.5f * (mnz + mxz);
    float d = sqrtf((x-cx)*(x-cx) + (y-cy)*(y-cy) + (z-cz)*(z-cz));
    #pragma unroll
    for (int m = 1; m <= 8; m <<= 1) d = fmaxf(d, __shfl_xor(d, m, 64));
    if (pos == 0) sgball[gid] = make_float4(cx, cy, cz, d);
}

// ---- query kernel: barrier-free one-wave blocks, register pools ----
// Round-6: kill the serialized selection spine. R2->R5 cut Phase-B work 4x
// with zero duration change: the limiter was merge_tau on a half-wave
// (break-dependent LDS loads, ~5-15K cyc) x2 per block while 3.5 waves sat
// at 6 barriers, stacked 8 blocks/CU. New structure: 8 queries per wave,
// 8 lanes/query, per-lane sorted-17 register pool (union over a query's 8
// lanes provably contains its true top-17), exact 17th via a 17-round shfl
// tournament (register-only, parallel everywhere). No barriers, no LDS key
// buffer, no merge; only LDS is the 1KB ballot-compacted subgroup list.
__global__ __launch_bounds__(64, 4)
void pel_query(const float4* __restrict__ P4r, const float4* __restrict__ P4p,
               const float4* __restrict__ sgball,
               float* __restrict__ acc_ws, unsigned* __restrict__ bcnt,
               float* __restrict__ out)
{
    __shared__ unsigned short s_list[NSG];        // 1 KB

    const int lane = threadIdx.x;
    const int lq = lane >> 3, sp = lane & 7;      // query, 8 lanes each
    const int q  = blockIdx.x * QPW + lq;
    const int b  = q >> 13;
    const int i  = q & (NPTS - 1);

    const float4* __restrict__ Pq = P4r + b * NPTS;
    const float4* __restrict__ Pp = P4p + b * NPTS;
    const float4* __restrict__ Sg = sgball + b * NSG;

    const float4 self = Pq[i];
    const float xi = -0.5f * self.x, yi = -0.5f * self.y, zi = -0.5f * self.z;
    const float sqi = self.w;

    // ---- Phase W: conservative tau bound from 64-pt Morton window ----
    // per-lane sorted-3 of its 8 window keys; bound = 2nd-largest of the
    // 8 lanes' 3rd-smallest  =>  >= 7 lanes have >=3 keys <= bound => >=21
    // window keys <= bound  =>  bound >= true 17th  (filter superset holds).
    unsigned a3[3] = {~0u, ~0u, ~0u};
    const int wln = min(max(i - WIN / 2, 0), NPTS - WIN) + sp * 8;
    #pragma unroll
    for (int u = 0; u < 8; ++u) {
        const unsigned key = mkkey(Pq[wln + u], xi, yi, zi, sqi, (unsigned)(wln + u));
        a3[2] = min(a3[2], max(a3[1], key));
        a3[1] = min(a3[1], max(a3[0], key));
        a3[0] = min(a3[0], key);
    }
    unsigned tb;
    {
        const unsigned v0  = a3[2];
        const unsigned v1  = (unsigned)__shfl_xor((int)v0, 1, 64);
        const unsigned A   = max(v0, v1), B = min(v0, v1);
        const unsigned A2  = (unsigned)__shfl_xor((int)A, 2, 64);
        const unsigned B2  = (unsigned)__shfl_xor((int)B, 2, 64);
        const unsigned S   = max(A, A2);                      // max of 4
        const unsigned U   = max(min(A, A2), max(B, B2));     // 2nd of 4
        const unsigned S4  = (unsigned)__shfl_xor((int)S, 4, 64);
        const unsigned U4  = (unsigned)__shfl_xor((int)U, 4, 64);
        tb = max(min(S, S4), max(U, U4));                     // 2nd of 8
    }
    const unsigned bound = tb;
    const float rt = sqrtf(__uint_as_float((bound & EMASK) + 0x2000u));

    // ---- Phase G: wave ball over the 8 queries (registers only) ----
    float mnx = xi, mxx = xi, mny = yi, mxy = yi, mnz = zi, mxz = zi;
    #pragma unroll
    for (int m = 1; m <= 32; m <<= 1) {
        mnx = fminf(mnx, __shfl_xor(mnx, m, 64)); mxx = fmaxf(mxx, __shfl_xor(mxx, m, 64));
        mny = fminf(mny, __shfl_xor(mny, m, 64)); mxy = fmaxf(mxy, __shfl_xor(mxy, m, 64));
        mnz = fminf(mnz, __shfl_xor(mnz, m, 64)); mxz = fmaxf(mxz, __shfl_xor(mxz, m, 64));
    }
    const float cxw = 0.5f * (mnx + mxx), cyw = 0.5f * (mny + mxy), czw = 0.5f * (mnz + mxz);
    float v = sqrtf((xi-cxw)*(xi-cxw) + (yi-cyw)*(yi-cyw) + (zi-czw)*(zi-czw)) + rt;
    #pragma unroll
    for (int m = 1; m <= 32; m <<= 1) v = fmaxf(v, __shfl_xor(v, m, 64));
    const float Rq = v + 1e-3f;

    // ---- Phase F: 512 ball tests (8/lane), ballot-compact IDs ----
    int ng = 0;
    #pragma unroll
    for (int r = 0; r < NSG / 64; ++r) {
        const int k2 = r * 64 + lane;
        const float4 gb = Sg[k2];
        const float dx = gb.x - cxw, dy = gb.y - cyw, dz = gb.z - czw;
        const float rhs = Rq + gb.w;
        const bool acc = (dx*dx + dy*dy + dz*dz <= rhs * rhs);
        const unsigned long long mask = __ballot(acc);
        if (acc)
            s_list[ng + (int)__popcll(mask & ((1ull << lane) - 1ull))] = (unsigned short)k2;
        ng += (int)__popcll(mask);
    }
    __syncthreads();   // one-wave block: just drains LDS writes

    // ---- Phase B: push into per-lane sorted-17 register pool ----
    // lane handles pts sp*2, sp*2+1 of every listed subgroup. Pruning with
    // tauL = min(bound, own 17th) is safe: a key beaten by 17 keys of the
    // same lane (same query) can't be in the query's top-17.
    unsigned c17[KK];
    #pragma unroll
    for (int k = 0; k < KK; ++k) c17[k] = 0xFFFFFFFFu;
    unsigned tauL = bound;
    const int sp2 = sp * 2;
    int j0 = (int)s_list[0] * SGS + sp2;
    int j1 = (int)s_list[min(1, ng - 1)] * SGS + sp2;
    float4 c0a = Pq[j0], c0b = Pq[j0 + 1];
    float4 c1a = Pq[j1], c1b = Pq[j1 + 1];
    for (int e = 0; e < ng; ++e) {
        const int jn = (int)s_list[min(e + 2, ng - 1)] * SGS + sp2;   // depth-2 prefetch
        const float4 nxa = Pq[jn], nxb = Pq[jn + 1];
        unsigned key = mkkey(c0a, xi, yi, zi, sqi, (unsigned)j0);
        if (key <= tauL) { ins17(c17, key); tauL = min(tauL, c17[KK - 1]); }
        key = mkkey(c0b, xi, yi, zi, sqi, (unsigned)(j0 + 1));
        if (key <= tauL) { ins17(c17, key); tauL = min(tauL, c17[KK - 1]); }
        c0a = c1a; c0b = c1b; j0 = j1;
        c1a = nxa; c1b = nxb; j1 = jn;
    }

    // ---- Phase C: exact per-query 17th via 17-round lane tournament ----
    // 8 sorted pools; each round takes the min of the 8 heads (keys unique:
    // index embedded), the winning lane pops (static predicated shift).
    unsigned cpy[KK];
    #pragma unroll
    for (int k = 0; k < KK; ++k) cpy[k] = c17[k];
    unsigned tauK = 0xFFFFFFFFu;
    for (int r = 0; r < KK; ++r) {
        const unsigned h  = cpy[0];
        unsigned m1 = min(h,  (unsigned)__shfl_xor((int)h,  1, 64));
        m1          = min(m1, (unsigned)__shfl_xor((int)m1, 2, 64));
        const unsigned w = min(m1, (unsigned)__shfl_xor((int)m1, 4, 64));
        const bool won = (h == w);
        #pragma unroll
        for (int k = 0; k < KK - 1; ++k) cpy[k] = won ? cpy[k + 1] : cpy[k];
        cpy[KK - 1] = won ? 0xFFFFFFFFu : cpy[KK - 1];
        tauK = w;
    }

    // ---- Phase D: full-precision |dr - dp| over this lane's final keys ----
    const float4 selfp = Pp[i];
    const float pxi = -0.5f * selfp.x, pyi = -0.5f * selfp.y, pzi = -0.5f * selfp.z;
    float accv = 0.0f;
    #pragma unroll
    for (int k = 0; k < KK; ++k) {
        if (c17[k] <= tauK) {
            const int j = (int)(c17[k] & JMASK);
            const float4 pr = Pq[j];
            const float er  = fmaf(pr.x, xi, fmaf(pr.y, yi, pr.z * zi)) + pr.w;
            const float d2r = fmaxf(er + sqi, 0.0f);
            const float4 pp = Pp[j];
            const float ep  = fmaf(pp.x, pxi, fmaf(pp.y, pyi, pp.z * pzi)) + pp.w;
            const float d2p = fmaxf(ep + selfp.w, 0.0f);
            accv += fabsf(sqrtf(d2r) - sqrtf(d2p));
        }
    }

    #pragma unroll
    for (int o = 32; o > 0; o >>= 1) accv += __shfl_down(accv, o, 64);
    if (lane == 0) {
        atomicAdd(acc_ws, accv);
        __threadfence();
        const unsigned old = atomicAdd(bcnt, 1u);
        if (old == GRIDQ - 1) {
            __threadfence();
            const float total = atomicAdd(acc_ws, 0.0f);
            out[0] = total * (1.0f / (float)TOTAL_EDGES);
        }
    }
}

extern "C" void kernel_launch(void* const* d_in, const int* in_sizes, int n_in,
                              void* d_out, int out_size, void* d_ws, size_t ws_size,
                              hipStream_t stream) {
    const float* pref = (const float*)d_in[0];
    const float* pts  = (const float*)d_in[1];
    // ws: [P4r 512K (alias hist)][P4p 512K][off 512K (alias sgball 32K)][acc,bcnt]
    float4*   P4r  = (float4*)d_ws;
    float4*   P4p  = P4r + NQ;
    unsigned* hist = (unsigned*)d_ws;                      // dead after scan
    unsigned* off  = (unsigned*)((char*)d_ws + 1048576);   // dead after scatter
    float4*   sgball = (float4*)((char*)d_ws + 1048576);   // written by gstat
    float*    acc  = (float*)((char*)d_ws + 1581056);
    unsigned* bcnt = (unsigned*)(acc + 1);
    float*    out  = (float*)d_out;

    hipMemsetAsync(hist, 0, BATCH * NCELL * sizeof(unsigned), stream);
    pel_hist   <<<NQ / 256, 256, 0, stream>>>(pref, hist, acc, bcnt);
    pel_scan   <<<BATCH, 1024, 0, stream>>>(hist, off);
    pel_scatter<<<NQ / 256, 256, 0, stream>>>(pref, pts, off, P4r, P4p);
    pel_gstat  <<<(BATCH * NSG) / 16, 256, 0, stream>>>(P4r, sgball);
    pel_query  <<<GRIDQ, 64, 0, stream>>>(P4r, P4p, sgball, acc, bcnt, out);
}

// Round 7
// 261.894 us; speedup vs baseline: 1.1819x; 1.1819x over previous
//
#include <hip/hip_runtime.h>
#include <math.h>

#define BATCH 4
#define NPTS  8192
#define KNN   16
#define KK    17               // top-17 incl. self (self key: d2 = +0 exactly)
#define NQ    (BATCH*NPTS)     // 32768
#define JMASK 0x1FFFu
#define EMASK 0xFFFFE000u      // top 19 bits of d2 (d2 >= +0 -> uint-sortable)
#define TOTAL_EDGES (BATCH*NPTS*KNN)

#define GC    32
#define GLO   (-4.5f)
#define GINV  (32.0f/9.0f)
#define NCELL (GC*GC*GC)

#define QPB   64               // queries per block (Morton-consecutive)
#define BLOCK 512              // 8 waves; thread (w,l): query l, point-slice w
#define NWAVE 8
#define SLICE (NPTS/NWAVE)     // 1024 points per thread sweep
#define GRIDQ (NQ/QPB)         // 512 blocks
#define WIN   64               // tau0 window (sorted-index neighbors)

__device__ __forceinline__ int cell_coord(float x) {
    int c = (int)floorf((x - GLO) * GINV);
    return min(GC - 1, max(0, c));
}
__device__ __forceinline__ unsigned spread5(unsigned v) {
    v &= 31u;
    v = (v | (v << 8)) & 0x100Fu;
    v = (v | (v << 4)) & 0x10C3u;
    v = (v | (v << 2)) & 0x1249u;
    return v;
}
__device__ __forceinline__ unsigned morton_id(float x, float y, float z) {
    return spread5((unsigned)cell_coord(x)) | (spread5((unsigned)cell_coord(y)) << 1)
         | (spread5((unsigned)cell_coord(z)) << 2);
}
// p = (-2xj,-2yj,-2zj,sqj); key = truncated d2 | index (self -> d2 = +0 exact)
__device__ __forceinline__ unsigned mkkey(const float4 p, float xi, float yi,
                                          float zi, float sqi, unsigned j) {
    const float e  = fmaf(p.x, xi, fmaf(p.y, yi, p.z * zi)) + p.w;
    const float d2 = e + sqi;
    return (__float_as_uint(d2) & EMASK) | j;
}
__device__ __forceinline__ void ins17(unsigned (&a)[KK], unsigned key) {
    #pragma unroll
    for (int k = KK - 1; k >= 1; --k) a[k] = min(a[k], max(a[k - 1], key));
    a[0] = min(a[0], key);
}

// ---- build kernels (verified, absmax 0.0) ----
__global__ void pel_hist(const float* __restrict__ pref, unsigned* __restrict__ hist,
                         float* __restrict__ acc, unsigned* __restrict__ bcnt) {
    const int idx = blockIdx.x * 256 + threadIdx.x;
    if (idx == 0) { acc[0] = 0.0f; bcnt[0] = 0u; }
    const int b = idx >> 13;
    const unsigned mid = morton_id(pref[3*idx], pref[3*idx+1], pref[3*idx+2]);
    atomicAdd(&hist[b * NCELL + mid], 1u);
}
__global__ __launch_bounds__(1024)
void pel_scan(const unsigned* __restrict__ hist, unsigned* __restrict__ off) {
    __shared__ unsigned s[1024];
    const unsigned* h = hist + blockIdx.x * NCELL;
    unsigned*       o = off  + blockIdx.x * NCELL;
    const int t = threadIdx.x;
    unsigned v[32], tot = 0;
    #pragma unroll
    for (int k = 0; k < 32; ++k) { v[k] = h[t * 32 + k]; tot += v[k]; }
    s[t] = tot;
    __syncthreads();
    for (int d = 1; d < 1024; d <<= 1) {
        const unsigned add = (t >= d) ? s[t - d] : 0u;
        __syncthreads();
        s[t] += add;
        __syncthreads();
    }
    unsigned run = s[t] - tot;
    #pragma unroll
    for (int k = 0; k < 32; ++k) { o[t * 32 + k] = run; run += v[k]; }
}
__global__ void pel_scatter(const float* __restrict__ pref, const float* __restrict__ pts,
                            unsigned* __restrict__ off,
                            float4* __restrict__ p4r, float4* __restrict__ p4p) {
    const int idx = blockIdx.x * 256 + threadIdx.x;
    const int b = idx >> 13;
    const float x = pref[3*idx], y = pref[3*idx+1], z = pref[3*idx+2];
    const unsigned mid = morton_id(x, y, z);
    const unsigned pos = atomicAdd(&off[b * NCELL + mid], 1u);
    p4r[b * NPTS + pos] = make_float4(-2.f*x, -2.f*y, -2.f*z, fmaf(x, x, fmaf(y, y, z*z)));
    const float px = pts[3*idx], py = pts[3*idx+1], pz = pts[3*idx+2];
    p4p[b * NPTS + pos] = make_float4(-2.f*px, -2.f*py, -2.f*pz,
                                      fmaf(px, px, fmaf(py, py, pz*pz)));
}

// ---- query kernel: uniform-work exact brute force, 8-way partitioned ----
// Round-7: R2->R6 varied candidate volume (4x), barriers (6->0), bank
// conflicts (3M->0) and selection structure; duration never left 190-245us.
// The invariant was data-dependent filter work (tail waves 10x average).
// Now: NO filter. Thread (w,l) sweeps point-slice [w*1024,(w+1)*1024) for
// query l with a register sorted-17, pruned by tau0 = exact 17th of the
// 64-pt Morton window (makes inserts rare and pass-iterations clustered ->
// s_cbranch skips). One barrier; owners merge the 8 sorted partials
// (early-break) -> exact top-17; Phase D split by rank. 268M pairs x ~8
// VALU ~= 27us issue-bound floor, identical work per thread, no tail.
__global__ __launch_bounds__(BLOCK, 4)
void pel_query(const float4* __restrict__ P4r, const float4* __restrict__ P4p,
               float* __restrict__ acc_ws, unsigned* __restrict__ bcnt,
               float* __restrict__ out)
{
    __shared__ unsigned s_pool[KK][BLOCK];        // 34 KB
    __shared__ float s_part[NWAVE];

    const int t = threadIdx.x;
    const int l = t & 63, w = t >> 6;
    const int q = blockIdx.x * QPB + l;
    const int b = q >> 13;
    const int i = q & (NPTS - 1);

    const float4* __restrict__ Pq = P4r + b * NPTS;
    const float4* __restrict__ Pp = P4p + b * NPTS;

    const float4 self = Pq[i];
    const float xi = -0.5f * self.x, yi = -0.5f * self.y, zi = -0.5f * self.z;
    const float sqi = self.w;

    // ---- Phase W: tau0 = exact 17th of the 64-pt Morton window (regs) ----
    unsigned t17[KK];
    #pragma unroll
    for (int k = 0; k < KK; ++k) t17[k] = 0xFFFFFFFFu;
    const int w0 = min(max(i - WIN / 2, 0), NPTS - WIN);
    for (int u = 0; u < WIN; ++u) {
        const unsigned key = mkkey(Pq[w0 + u], xi, yi, zi, sqi, (unsigned)(w0 + u));
        if (key <= t17[KK - 1]) ins17(t17, key);
    }
    unsigned tauL = t17[KK - 1];   // >= true 17th (window is a subset)

    // ---- Phase B: sweep my 1024-pt slice, register sorted-17 pool ----
    // Streaming top-k: a key rejected by (tauL = min(tau0, own 17th)) cannot
    // be in this slice's top-17, hence not in the query's top-17. Union of
    // the 8 slice pools contains the true top-17. Depth-1 4-pt prefetch.
    unsigned c17[KK];
    #pragma unroll
    for (int k = 0; k < KK; ++k) c17[k] = 0xFFFFFFFFu;
    const int jb = w << 10;
    float4 p0 = Pq[jb], p1 = Pq[jb + 1], p2 = Pq[jb + 2], p3 = Pq[jb + 3];
    for (int j = 0; j < SLICE; j += 4) {
        const int jn = jb + ((j + 4) & (SLICE - 1));   // wraps on last iter
        const float4 n0 = Pq[jn],     n1 = Pq[jn + 1];
        const float4 n2 = Pq[jn + 2], n3 = Pq[jn + 3];
        unsigned key;
        key = mkkey(p0, xi, yi, zi, sqi, (unsigned)(jb + j));
        if (key <= tauL) { ins17(c17, key); tauL = min(tauL, c17[KK - 1]); }
        key = mkkey(p1, xi, yi, zi, sqi, (unsigned)(jb + j + 1));
        if (key <= tauL) { ins17(c17, key); tauL = min(tauL, c17[KK - 1]); }
        key = mkkey(p2, xi, yi, zi, sqi, (unsigned)(jb + j + 2));
        if (key <= tauL) { ins17(c17, key); tauL = min(tauL, c17[KK - 1]); }
        key = mkkey(p3, xi, yi, zi, sqi, (unsigned)(jb + j + 3));
        if (key <= tauL) { ins17(c17, key); tauL = min(tauL, c17[KK - 1]); }
        p0 = n0; p1 = n1; p2 = n2; p3 = n3;
    }

    // ---- Phase C: publish partials, merge 8 sorted pools -> exact 17 ----
    #pragma unroll
    for (int k = 0; k < KK; ++k) s_pool[k][t] = c17[k];
    __syncthreads();
    #pragma unroll 1
    for (int d = 1; d < NWAVE; ++d) {
        const int t2 = (((w + d) & (NWAVE - 1)) << 6) | l;
        #pragma unroll 1
        for (int k = 0; k < KK; ++k) {
            const unsigned vk = s_pool[k][t2];
            if (vk >= c17[KK - 1]) break;   // sorted source: nothing more fits
            ins17(c17, vk);
        }
    }
    // c17 = exact sorted top-17 incl self, identical across the 8 owners
    // (pure integer min/max; slices disjoint -> keys unique -> unique set)

    // ---- Phase D: |dr - dp| over ranks w, w+8, w+16 of the shared list ----
    const float4 selfp = Pp[i];
    const float pxi = -0.5f * selfp.x, pyi = -0.5f * selfp.y, pzi = -0.5f * selfp.z;
    float accv = 0.0f;
    for (int r = w; r < KK; r += NWAVE) {
        const int j = (int)(c17[r] & JMASK);
        const float4 pr = Pq[j];
        const float er  = fmaf(pr.x, xi, fmaf(pr.y, yi, pr.z * zi)) + pr.w;
        const float d2r = fmaxf(er + sqi, 0.0f);
        const float4 pp = Pp[j];
        const float ep  = fmaf(pp.x, pxi, fmaf(pp.y, pyi, pp.z * pzi)) + pp.w;
        const float d2p = fmaxf(ep + selfp.w, 0.0f);
        accv += fabsf(sqrtf(d2r) - sqrtf(d2p));   // self term contributes 0
    }

    #pragma unroll
    for (int o = 32; o > 0; o >>= 1) accv += __shfl_down(accv, o, 64);
    if (l == 0) s_part[w] = accv;
    __syncthreads();
    if (t == 0) {
        float s = 0.0f;
        #pragma unroll
        for (int w2 = 0; w2 < NWAVE; ++w2) s += s_part[w2];
        atomicAdd(acc_ws, s);
        __threadfence();
        const unsigned old = atomicAdd(bcnt, 1u);
        if (old == GRIDQ - 1) {
            __threadfence();
            const float total = atomicAdd(acc_ws, 0.0f);
            out[0] = total * (1.0f / (float)TOTAL_EDGES);
        }
    }
}

extern "C" void kernel_launch(void* const* d_in, const int* in_sizes, int n_in,
                              void* d_out, int out_size, void* d_ws, size_t ws_size,
                              hipStream_t stream) {
    const float* pref = (const float*)d_in[0];
    const float* pts  = (const float*)d_in[1];
    // ws: [P4r 512K (alias hist)][P4p 512K][off 512K][acc,bcnt]
    float4*   P4r  = (float4*)d_ws;
    float4*   P4p  = P4r + NQ;
    unsigned* hist = (unsigned*)d_ws;                      // dead after scan
    unsigned* off  = (unsigned*)((char*)d_ws + 1048576);   // dead after scatter
    float*    acc  = (float*)((char*)d_ws + 1581056);
    unsigned* bcnt = (unsigned*)(acc + 1);
    float*    out  = (float*)d_out;

    hipMemsetAsync(hist, 0, BATCH * NCELL * sizeof(unsigned), stream);
    pel_hist   <<<NQ / 256, 256, 0, stream>>>(pref, hist, acc, bcnt);
    pel_scan   <<<BATCH, 1024, 0, stream>>>(hist, off);
    pel_scatter<<<NQ / 256, 256, 0, stream>>>(pref, pts, off, P4r, P4p);
    pel_query  <<<GRIDQ, BLOCK, 0, stream>>>(P4r, P4p, acc, bcnt, out);
}